// Round 8
// baseline (329.096 us; speedup 1.0000x reference)
//
#include <hip/hip_runtime.h>
#include <hip/hip_bf16.h>
#include <math.h>

// Problem constants (B=4, H=W=64, C=128, DI=256, N=16, R=8, K=4)
// BATCHED over the 2 streams: 8 images, 32768 rows, 32 bk channel-groups.
#define DDIM 256
#define NCH  128
#define LCH  32

typedef __attribute__((ext_vector_type(8))) short bf8_t;
typedef __attribute__((ext_vector_type(4))) float f32x4;
typedef __attribute__((ext_vector_type(8))) unsigned short u16x8;
typedef _Float16 f16;

__device__ __forceinline__ float silu_f(float x) {
    return x / (1.f + __expf(-x));
}
__device__ __forceinline__ float softplus_f(float x) {
    return fmaxf(x, 0.f) + __logf(1.f + __expf(-fabsf(x)));
}
__device__ __forceinline__ unsigned short f2b(float x) {
    union { __hip_bfloat16 h; unsigned short u; } v;
    v.h = __float2bfloat16(x);
    return v.u;
}
__device__ __forceinline__ float b2f(unsigned short u) {
    union { float f; unsigned int i; } v;
    v.i = ((unsigned int)u) << 16;
    return v.f;
}
__device__ __forceinline__ int perm_idx(int k, int l) {
    switch (k & 3) {
        case 0: return l;
        case 1: return ((l & 63) << 6) | (l >> 6);
        case 2: return 4095 - l;
        default: { int lr = 4095 - l; return ((lr & 63) << 6) | (lr >> 6); }
    }
}
// dA[n] = e1^(n+1), log-depth mul tree
__device__ __forceinline__ void pow_geom(float e1, float dA[16]) {
    const float e2 = e1 * e1, e4 = e2 * e2, e8 = e4 * e4;
    dA[0] = e1;       dA[1] = e2;       dA[2] = e2 * e1;  dA[3] = e4;
    dA[4] = e4 * e1;  dA[5] = e4 * e2;  dA[6] = e4 * dA[2]; dA[7] = e8;
    dA[8] = e8 * e1;  dA[9] = e8 * e2;  dA[10] = e8 * dA[2]; dA[11] = e8 * e4;
    dA[12] = e8 * dA[4]; dA[13] = e8 * dA[5]; dA[14] = e8 * dA[6]; dA[15] = e8 * e8;
}
__device__ __forceinline__ float delta_of(const float* pr0, const float4 w0,
                                          const float4 w1, float bias) {
    const float4 p0 = *(const float4*)pr0;
    const float4 p1 = *(const float4*)(pr0 + 4);
    float x = bias;
    x = fmaf(p0.x, w0.x, x); x = fmaf(p0.y, w0.y, x);
    x = fmaf(p0.z, w0.z, x); x = fmaf(p0.w, w0.w, x);
    x = fmaf(p1.x, w1.x, x); x = fmaf(p1.y, w1.y, x);
    x = fmaf(p1.z, w1.z, x); x = fmaf(p1.w, w1.w, x);
    return softplus_f(x);
}
__device__ __forceinline__ bool geom_check(const float* Alogs, int kd, float& a0) {
    a0 = -__expf(Alogs[(size_t)kd * 16]);
    bool g = true;
    #pragma unroll
    for (int n = 1; n < 16; ++n) {
        const float an = -__expf(Alogs[(size_t)kd * 16 + n]);
        const float rr = a0 * (float)(n + 1);
        g = g && (fabsf(an - rr) <= 1e-4f * fabsf(rr));
    }
    return g;
}

// ---------------------------------------------------------------------------
// Convert all 5 weight tensors fp32->bf16 in one launch.
// segments (groups of 8): in0 8192 | in1 8192 | xp 5120 | out0 4096 | out1 4096
// ---------------------------------------------------------------------------
__global__ __launch_bounds__(256) void cvt_all(
    const float* __restrict__ s0, const float* __restrict__ s1,
    const float* __restrict__ s2, const float* __restrict__ s3,
    const float* __restrict__ s4, unsigned short* __restrict__ w) {
    const int i = blockIdx.x * 256 + threadIdx.x;
    const float* src; size_t so, oo;
    if (i < 8192)       { src = s0; so = i;         oo = 0; }
    else if (i < 16384) { src = s1; so = i - 8192;  oo = 65536; }
    else if (i < 21504) { src = s2; so = i - 16384; oo = 131072; }
    else if (i < 25600) { src = s3; so = i - 21504; oo = 172032; }
    else if (i < 29696) { src = s4; so = i - 25600; oo = 204800; }
    else return;
    const float4 a = ((const float4*)src)[so * 2];
    const float4 b = ((const float4*)src)[so * 2 + 1];
    u16x8 r;
    r[0] = f2b(a.x); r[1] = f2b(a.y); r[2] = f2b(a.z); r[3] = f2b(a.w);
    r[4] = f2b(b.x); r[5] = f2b(b.y); r[6] = f2b(b.z); r[7] = f2b(b.w);
    *(u16x8*)(w + oo + so * 8) = r;
}

// ---------------------------------------------------------------------------
// bf16 MFMA GEMM (batched 2-stream): out[m,n] = sum_k A[m,k] * W[n,k].
// W (and fp32-A source) selected per 128-row tile by m0>=msplit.
// EPI=0: plain f32 store. EPI=1: in_proj split (xc f32 | silu->bf16 z).
// EPI=2: out_proj, per-stream output offset.
// ---------------------------------------------------------------------------
template <int EPI, bool AF32>
__global__ __launch_bounds__(256) void gemm_bf(
    const unsigned short* __restrict__ A,
    const float* __restrict__ Af0, const float* __restrict__ Af1,
    const unsigned short* __restrict__ W0, const unsigned short* __restrict__ W1,
    float* __restrict__ out0, unsigned short* __restrict__ out1b,
    int N, int K, int msplit) {
    __shared__ unsigned short As[128][40];
    __shared__ unsigned short Bs[128][40];
    const int tid = threadIdx.x;
    const int lane = tid & 63;
    const int wid = tid >> 6;
    const int wr = wid >> 1, wc = wid & 1;
    const int m0 = blockIdx.y << 7, n0 = blockIdx.x << 7;
    const int sidx = (m0 >= msplit) ? 1 : 0;
    const int rbase = sidx ? msplit : 0;
    const float* Af = sidx ? Af1 : Af0;
    const unsigned short* W = sidx ? W1 : W0;
    const int r = lane & 15, g = lane >> 4;
    f32x4 acc[4][4];
    #pragma unroll
    for (int i = 0; i < 4; ++i)
        #pragma unroll
        for (int j = 0; j < 4; ++j) acc[i][j] = (f32x4){0.f, 0.f, 0.f, 0.f};
    const int row0 = tid >> 2;       // 0..63
    const int cc = (tid & 3) << 3;   // 0,8,16,24

    for (int k0 = 0; k0 < K; k0 += 32) {
        #pragma unroll
        for (int h = 0; h < 2; ++h) {
            const int row = row0 + (h << 6);
            u16x8 va;
            if (AF32) {
                const float* ap = Af + (size_t)(m0 + row - rbase) * K + k0 + cc;
                const float4 a0 = *(const float4*)ap;
                const float4 a1 = *(const float4*)(ap + 4);
                va[0] = f2b(a0.x); va[1] = f2b(a0.y);
                va[2] = f2b(a0.z); va[3] = f2b(a0.w);
                va[4] = f2b(a1.x); va[5] = f2b(a1.y);
                va[6] = f2b(a1.z); va[7] = f2b(a1.w);
            } else {
                va = *(const u16x8*)(A + (size_t)(m0 + row) * K + k0 + cc);
            }
            *(u16x8*)(&As[row][cc]) = va;
            const int nrow = n0 + row;
            u16x8 vb = (u16x8){0, 0, 0, 0, 0, 0, 0, 0};
            if (nrow < N) vb = *(const u16x8*)(W + (size_t)nrow * K + k0 + cc);
            *(u16x8*)(&Bs[row][cc]) = vb;
        }
        __syncthreads();
        bf8_t af[4], bfr[4];
        #pragma unroll
        for (int i = 0; i < 4; ++i)
            af[i] = *(const bf8_t*)(&As[(wr << 6) + (i << 4) + r][g << 3]);
        #pragma unroll
        for (int j = 0; j < 4; ++j)
            bfr[j] = *(const bf8_t*)(&Bs[(wc << 6) + (j << 4) + r][g << 3]);
        #pragma unroll
        for (int i = 0; i < 4; ++i)
            #pragma unroll
            for (int j = 0; j < 4; ++j)
                acc[i][j] = __builtin_amdgcn_mfma_f32_16x16x32_bf16(
                    af[i], bfr[j], acc[i][j], 0, 0, 0);
        __syncthreads();
    }
    // epilogue: C/D layout col=lane&15, row=(lane>>4)*4+reg
    #pragma unroll
    for (int i = 0; i < 4; ++i) {
        const int mrow = m0 + (wr << 6) + (i << 4) + (g << 2);
        #pragma unroll
        for (int j = 0; j < 4; ++j) {
            const int col = n0 + (wc << 6) + (j << 4) + r;
            if (EPI != 1 && col >= N) continue;
            #pragma unroll
            for (int q = 0; q < 4; ++q) {
                const float v = acc[i][j][q];
                const int mm = mrow + q;
                if (EPI == 0) {
                    out0[(size_t)mm * N + col] = v;
                } else if (EPI == 1) {
                    if (col < 256) out0[((size_t)mm << 8) + col] = v;
                    else out1b[((size_t)mm << 8) + (col - 256)] = f2b(silu_f(v));
                } else {
                    out0[(size_t)sidx * 2097152 +
                         ((size_t)(mm - rbase) << 7) + col] = v;
                }
            }
        }
    }
}

// ---------------------------------------------------------------------------
// Depthwise 3x3 conv (SAME) + bias + SiLU, batched; weights per stream.
// ---------------------------------------------------------------------------
__global__ __launch_bounds__(256) void dwconv_silu(
    const float* __restrict__ in,
    const float* __restrict__ w0, const float* __restrict__ b0,
    const float* __restrict__ w1, const float* __restrict__ b1,
    float* __restrict__ outf) {
    const int d = threadIdx.x;
    const int bp = blockIdx.x;            // [0, 32768)
    const int b = bp >> 12;               // [0, 8)
    const float* w = (b >= 4) ? w1 : w0;
    const float* bias = (b >= 4) ? b1 : b0;
    const int sp = bp & 4095;
    const int h = sp >> 6, wc = sp & 63;
    float acc = bias[d];
    #pragma unroll
    for (int kh = 0; kh < 3; ++kh) {
        const int hh = h + kh - 1;
        if (hh < 0 || hh >= 64) continue;
        #pragma unroll
        for (int kw = 0; kw < 3; ++kw) {
            const int ww = wc + kw - 1;
            if (ww < 0 || ww >= 64) continue;
            acc = fmaf(in[(size_t)(((b << 12) + (hh << 6) + ww)) * DDIM + d],
                       w[d * 9 + kh * 3 + kw], acc);
        }
    }
    outf[(size_t)bp * DDIM + d] = silu_f(acc);
}

// ---------------------------------------------------------------------------
// Scan phase A: per-chunk local scan from h=0. hend in fp16, cumd f32.
// blockIdx = bk*NCH + c, bk in [0,32) (batched). Layout [c][bk][d][n].
// ---------------------------------------------------------------------------
__global__ __launch_bounds__(256) void scanA(
    const float* __restrict__ xc, const float* __restrict__ proj,
    const float* __restrict__ Alogs, const float* __restrict__ dtw,
    const float* __restrict__ dtb,
    f16* __restrict__ hend, float* __restrict__ cumd) {
    const int d = threadIdx.x;
    const int blk = blockIdx.x;
    const int c = blk & (NCH - 1);
    const int bk = blk >> 7;              // [0, 32)
    const int k = bk & 3;
    const int b = bk >> 2;                // [0, 8)
    const int kd = (k << 8) + d;

    float a0;
    const bool geom = geom_check(Alogs, kd, a0);
    const float4 w0 = *(const float4*)(dtw + (size_t)kd * 8);
    const float4 w1 = *(const float4*)(dtw + (size_t)kd * 8 + 4);
    const float bias = dtb[kd];

    float h[16];
    #pragma unroll
    for (int n = 0; n < 16; ++n) h[n] = 0.f;
    float cum = 0.f;
    const int l0 = c * LCH;
    const int boff = b << 12;

    if (geom) {
        for (int t = 0; t < LCH; ++t) {
            const int p = perm_idx(k, l0 + t);
            const int bpp = boff + p;
            const float* pr0 = proj + (size_t)bpp * 160 + k * 40;
            const float delta = delta_of(pr0, w0, w1, bias);
            const float u = xc[(size_t)bpp * DDIM + d];
            const float du = delta * u;
            cum += delta;
            float dA[16];
            pow_geom(__expf(delta * a0), dA);
            #pragma unroll
            for (int n = 0; n < 16; ++n)
                h[n] = fmaf(dA[n], h[n], du * pr0[8 + n]);
        }
    } else {
        for (int t = 0; t < LCH; ++t) {
            const int p = perm_idx(k, l0 + t);
            const int bpp = boff + p;
            const float* pr0 = proj + (size_t)bpp * 160 + k * 40;
            const float delta = delta_of(pr0, w0, w1, bias);
            const float u = xc[(size_t)bpp * DDIM + d];
            const float du = delta * u;
            cum += delta;
            #pragma unroll
            for (int n = 0; n < 16; ++n) {
                const float an = -__expf(Alogs[(size_t)kd * 16 + n]);
                h[n] = fmaf(__expf(delta * an), h[n], du * pr0[8 + n]);
            }
        }
    }
    const size_t o = ((size_t)(c * 32 + bk) * DDIM + d) * 16;
    u16x8 r0, r1;
    #pragma unroll
    for (int n = 0; n < 8; ++n) {
        union { f16 h; unsigned short u; } v0, v1;
        v0.h = (f16)h[n]; v1.h = (f16)h[n + 8];
        r0[n] = v0.u; r1[n] = v1.u;
    }
    *(u16x8*)((unsigned short*)hend + o) = r0;
    *(u16x8*)((unsigned short*)hend + o + 8) = r1;
    cumd[(size_t)(c * 32 + bk) * DDIM + d] = cum;
}

// ---------------------------------------------------------------------------
// Scan phase B: inter-chunk recurrence over 131072 states, IN PLACE on the
// fp16 buffer (read hend[c], then overwrite slot c with H0[c]).
// ---------------------------------------------------------------------------
__global__ __launch_bounds__(256) void scanB(
    f16* __restrict__ hh, const float* __restrict__ cumd,
    const float* __restrict__ Alogs) {
    const int tid = blockIdx.x * 256 + threadIdx.x;   // [0, 131072)
    const int n = tid & 15;
    const int d = (tid >> 4) & 255;
    const int bk = tid >> 12;
    const int k = bk & 3;
    const float a = -__expf(Alogs[(size_t)(((k << 8) + d)) * 16 + n]);
    const int cdix = tid >> 4;                        // bk*256+d
    float H = 0.f;
    for (int c = 0; c < NCH; c += 4) {
        float tmp[4], cd[4];
        #pragma unroll
        for (int j = 0; j < 4; ++j) {
            tmp[j] = (float)hh[(size_t)(c + j) * 131072 + tid];
            cd[j] = cumd[(size_t)(c + j) * 8192 + cdix];
        }
        #pragma unroll
        for (int j = 0; j < 4; ++j) {
            hh[(size_t)(c + j) * 131072 + tid] = (f16)H;
            H = fmaf(__expf(cd[j] * a), H, tmp[j]);
        }
    }
}

// ---------------------------------------------------------------------------
// Scan phase C chunk worker: run one chunk of direction k from its true
// initial state (fp16 H0). EMIT=0: y -> ybuf[t][d] (fp16). EMIT=1: emit
// ybuf[31-t][d] + y to fp16 ysp plane at spatial position.
// ---------------------------------------------------------------------------
template <int EMIT>
__device__ __forceinline__ void scanC_chunk(
    const int k, const int chunk, const int b, const int d,
    const float* __restrict__ xc, const float* __restrict__ proj,
    const float* __restrict__ Alogs, const float* __restrict__ dtw,
    const float* __restrict__ dtb, const float* __restrict__ Dsv,
    const f16* __restrict__ H0, f16* __restrict__ ysp,
    f16 (*ybuf)[256], const size_t planeBase) {
    const int kd = (k << 8) + d;
    const int bk = (b << 2) + k;

    float a0;
    const bool geom = geom_check(Alogs, kd, a0);
    const float4 w0 = *(const float4*)(dtw + (size_t)kd * 8);
    const float4 w1 = *(const float4*)(dtw + (size_t)kd * 8 + 4);
    const float bias = dtb[kd];
    const float Dd = Dsv[kd];

    float h[16];
    const size_t ho = ((size_t)(chunk * 32 + bk) * DDIM + d) * 16;
    {
        const u16x8 r0 = *(const u16x8*)((const unsigned short*)H0 + ho);
        const u16x8 r1 = *(const u16x8*)((const unsigned short*)H0 + ho + 8);
        #pragma unroll
        for (int n = 0; n < 8; ++n) {
            union { unsigned short u; f16 h; } v0, v1;
            v0.u = r0[n]; v1.u = r1[n];
            h[n] = (float)v0.h; h[n + 8] = (float)v1.h;
        }
    }
    const int l0 = chunk * LCH;
    const int boff = b << 12;

    if (geom) {
        for (int t = 0; t < LCH; ++t) {
            const int p = perm_idx(k, l0 + t);
            const int bpp = boff + p;
            const float* pr0 = proj + (size_t)bpp * 160 + k * 40;
            const float delta = delta_of(pr0, w0, w1, bias);
            const float u = xc[(size_t)bpp * DDIM + d];
            const float du = delta * u;
            float dA[16];
            pow_geom(__expf(delta * a0), dA);
            const float4 Ba = *(const float4*)(pr0 + 8);
            const float4 Bb = *(const float4*)(pr0 + 12);
            const float4 Bc = *(const float4*)(pr0 + 16);
            const float4 Bd = *(const float4*)(pr0 + 20);
            const float4 Ca = *(const float4*)(pr0 + 24);
            const float4 Cb = *(const float4*)(pr0 + 28);
            const float4 Cc = *(const float4*)(pr0 + 32);
            const float4 Cd = *(const float4*)(pr0 + 36);
            const float Bv[16] = {Ba.x,Ba.y,Ba.z,Ba.w, Bb.x,Bb.y,Bb.z,Bb.w,
                                  Bc.x,Bc.y,Bc.z,Bc.w, Bd.x,Bd.y,Bd.z,Bd.w};
            const float Cv[16] = {Ca.x,Ca.y,Ca.z,Ca.w, Cb.x,Cb.y,Cb.z,Cb.w,
                                  Cc.x,Cc.y,Cc.z,Cc.w, Cd.x,Cd.y,Cd.z,Cd.w};
            float y = 0.f;
            #pragma unroll
            for (int n = 0; n < 16; ++n) {
                h[n] = fmaf(dA[n], h[n], du * Bv[n]);
                y = fmaf(h[n], Cv[n], y);
            }
            y = fmaf(Dd, u, y);
            if (EMIT == 0) ybuf[t][d] = (f16)y;
            else ysp[planeBase + (size_t)p * DDIM + d] =
                     (f16)(y + (float)ybuf[31 - t][d]);
        }
    } else {
        for (int t = 0; t < LCH; ++t) {
            const int p = perm_idx(k, l0 + t);
            const int bpp = boff + p;
            const float* pr0 = proj + (size_t)bpp * 160 + k * 40;
            const float delta = delta_of(pr0, w0, w1, bias);
            const float u = xc[(size_t)bpp * DDIM + d];
            const float du = delta * u;
            float y = 0.f;
            #pragma unroll
            for (int n = 0; n < 16; ++n) {
                const float an = -__expf(Alogs[(size_t)kd * 16 + n]);
                h[n] = fmaf(__expf(delta * an), h[n], du * pr0[8 + n]);
                y = fmaf(h[n], pr0[24 + n], y);
            }
            y = fmaf(Dd, u, y);
            if (EMIT == 0) ybuf[t][d] = (f16)y;
            else ysp[planeBase + (size_t)p * DDIM + d] =
                     (f16)(y + (float)ybuf[31 - t][d]);
        }
    }
}

// ---------------------------------------------------------------------------
// Scan phase C, pair-fused: (k=pair, chunk c) then (k=pair+2, NCH-1-c);
// same 32-position window, pair-sum emitted to 16 fp16 planes.
// ybuf fp16 -> 16 KB LDS -> 8 blocks/CU (grid-capped, full occupancy).
// blockIdx = (b*2+pair)*NCH + c, b in [0,8).
// ---------------------------------------------------------------------------
__global__ __launch_bounds__(256) void scanC2(
    const float* __restrict__ xc, const float* __restrict__ proj,
    const float* __restrict__ Alogs, const float* __restrict__ dtw,
    const float* __restrict__ dtb, const float* __restrict__ Dsv,
    const f16* __restrict__ H0, f16* __restrict__ ysp) {
    __shared__ f16 ybuf[LCH][256];
    const int d = threadIdx.x;
    const int blk = blockIdx.x;
    const int c = blk & (NCH - 1);
    const int bp2 = blk >> 7;             // [0, 16)
    const int pair = bp2 & 1;
    const int b = bp2 >> 1;               // [0, 8)
    const size_t planeBase = (size_t)bp2 << 20;
    scanC_chunk<0>(pair, c, b, d, xc, proj, Alogs, dtw, dtb, Dsv, H0,
                   ysp, ybuf, planeBase);
    scanC_chunk<1>(pair + 2, NCH - 1 - c, b, d, xc, proj, Alogs, dtw, dtb,
                   Dsv, H0, ysp, ybuf, planeBase);
}

// ---------------------------------------------------------------------------
// Merge 2 pair-planes (fp16) + LayerNorm(D) + gate with bf16 z -> bf16 yz.
// ---------------------------------------------------------------------------
__global__ __launch_bounds__(256) void merge_ln(
    const f16* __restrict__ ysp, const unsigned short* __restrict__ z,
    const float* __restrict__ lnw, const float* __restrict__ lnb,
    unsigned short* __restrict__ yzb) {
    const int d = threadIdx.x;
    const int bp = blockIdx.x;            // [0, 32768)
    const int b = bp >> 12;               // [0, 8)
    const int p = bp & 4095;
    const float v =
        (float)ysp[(((size_t)(b << 1)) << 20) + (size_t)p * DDIM + d] +
        (float)ysp[(((size_t)(b << 1) + 1) << 20) + (size_t)p * DDIM + d];

    __shared__ float red[4];
    float s = v;
    #pragma unroll
    for (int o = 32; o > 0; o >>= 1) s += __shfl_xor(s, o);
    const int wave = threadIdx.x >> 6;
    if ((threadIdx.x & 63) == 0) red[wave] = s;
    __syncthreads();
    const float mu = (red[0] + red[1] + red[2] + red[3]) * (1.f / 256.f);
    __syncthreads();
    const float dv = v - mu;
    float s2 = dv * dv;
    #pragma unroll
    for (int o = 32; o > 0; o >>= 1) s2 += __shfl_xor(s2, o);
    if ((threadIdx.x & 63) == 0) red[wave] = s2;
    __syncthreads();
    const float var = (red[0] + red[1] + red[2] + red[3]) * (1.f / 256.f);
    const float y = dv * rsqrtf(var + 1e-5f) * lnw[d] + lnb[d];
    yzb[(size_t)bp * DDIM + d] = f2b(y * b2f(z[(size_t)bp * DDIM + d]));
}

// ---------------------------------------------------------------------------
extern "C" void kernel_launch(void* const* d_in, const int* in_sizes, int n_in,
                              void* d_out, int out_size, void* d_ws, size_t ws_size,
                              hipStream_t stream) {
    const float* xin0  = (const float*)d_in[0];
    const float* xin1  = (const float*)d_in[1];
    const float* inw0  = (const float*)d_in[2];
    const float* inw1  = (const float*)d_in[3];
    const float* convw0 = (const float*)d_in[4];
    const float* convb0 = (const float*)d_in[5];
    const float* convw1 = (const float*)d_in[6];
    const float* convb1 = (const float*)d_in[7];
    const float* xpw   = (const float*)d_in[8];
    const float* dtw   = (const float*)d_in[9];
    const float* dtb   = (const float*)d_in[10];
    const float* Alogs = (const float*)d_in[11];
    const float* Dsv   = (const float*)d_in[12];
    const float* lnw   = (const float*)d_in[13];
    const float* lnb   = (const float*)d_in[14];
    const float* outw0 = (const float*)d_in[15];
    const float* outw1 = (const float*)d_in[16];

    float* ws = (float*)d_ws;
    // layout (float offsets), total 35,770,368 floats = 143.1 MB:
    float* xc_raw  = ws + 0;             // 8,388,608  in_proj xc (dead after conv)
    f16*   ysp     = (f16*)(ws + 0);     //            16 fp16 planes (scanC->merge)
    unsigned short* zbuf = (unsigned short*)(ws + 8388608);  // 8.39M bf16
    float* xc_conv = ws + 12582912;      // 8,388,608  conv out (scan input)
    float* proj    = ws + 20971520;      // 5,242,880  x_proj out
    unsigned short* yzbf = (unsigned short*)(ws + 20971520); // after scanC
    f16*   hendH0  = (f16*)(ws + 26214400); // 16.78M fp16 (in-place hend->H0)
    float* cumd    = ws + 34603008;      // 1,048,576
    unsigned short* wreg = (unsigned short*)(ws + 35651584); // 237,568 bf16
    unsigned short* wbf_in0  = wreg + 0;
    unsigned short* wbf_in1  = wreg + 65536;
    unsigned short* wbf_xp   = wreg + 131072;
    unsigned short* wbf_out0 = wreg + 172032;
    unsigned short* wbf_out1 = wreg + 204800;
    float* outp = (float*)d_out;

    // 1: all weight conversions (one launch)
    cvt_all<<<116, 256, 0, stream>>>(inw0, inw1, xpw, outw0, outw1, wreg);
    // 2: in_proj, both streams (M=32768, N=512, K=128), fp32-A staging
    gemm_bf<1, true><<<dim3(4, 256), 256, 0, stream>>>(
        nullptr, xin0, xin1, wbf_in0, wbf_in1, xc_raw, zbuf, 512, 128, 16384);
    // 3: depthwise conv + silu (both streams)
    dwconv_silu<<<32768, 256, 0, stream>>>(xc_raw, convw0, convb0,
                                           convw1, convb1, xc_conv);
    // 4: x_proj (M=32768, N=160, K=256), fp32-A staging, shared W
    gemm_bf<0, true><<<dim3(2, 256), 256, 0, stream>>>(
        nullptr, xc_conv, xc_conv, wbf_xp, wbf_xp, proj, nullptr,
        160, 256, 1 << 30);
    // 5-7: chunked selective scan (both streams, fp16 state)
    scanA<<<32 * NCH, 256, 0, stream>>>(xc_conv, proj, Alogs, dtw, dtb,
                                        hendH0, cumd);
    scanB<<<512, 256, 0, stream>>>(hendH0, cumd, Alogs);
    scanC2<<<16 * NCH, 256, 0, stream>>>(xc_conv, proj, Alogs, dtw, dtb,
                                         Dsv, hendH0, ysp);
    // 8: merge pair-planes + LN + gate -> bf16
    merge_ln<<<32768, 256, 0, stream>>>(ysp, zbuf, lnw, lnb, yzbf);
    // 9: out_proj (M=32768, N=128, K=256), per-stream W and output offset
    gemm_bf<2, false><<<dim3(1, 256), 256, 0, stream>>>(
        yzbf, nullptr, nullptr, wbf_out0, wbf_out1, outp, nullptr,
        128, 256, 16384);
}